// Round 1
// baseline (666.523 us; speedup 1.0000x reference)
//
#include <hip/hip_runtime.h>

#define HASH_BINS 100000
#define EMBD 64
#define BATCH 262144
#define BM 64
#define LSTR 264  // LDS activation row stride (bf16 elems); 264*2=528B breaks 32-bank alignment

typedef __attribute__((ext_vector_type(8))) short short8;
typedef __attribute__((ext_vector_type(4))) float floatx4;
typedef __attribute__((ext_vector_type(4))) unsigned short ushortx4;

static __device__ __forceinline__ unsigned short f2bf(float f) {
  unsigned u = __builtin_bit_cast(unsigned, f);
  u += 0x7fff + ((u >> 16) & 1);  // round-to-nearest-even
  return (unsigned short)(u >> 16);
}
static __device__ __forceinline__ float bf2f(unsigned short b) {
  return __builtin_bit_cast(float, ((unsigned)b) << 16);
}

// ---------------- prep: build bf16 transposed/padded weights in ws ----------------
// ws layout (bytes):
//   0      : S   fp32 [128]            (rowsum of cross_k^2)
//   512    : Kt  bf16 [128][128]       (cross_k transposed)   } contiguous => combined
//   33280  : W1t bf16 [224][128]       (W1 transposed, N-pad) } [352][128] matrix
//   90624  : W2t bf16 [256][224]       (K-pad 200->224)
//   205312 : W3t bf16 [224][256]       (N-pad 200->224)
//   320000 : W4t bf16 [128][224]       (K-pad 200->224)
__global__ void dfm_prep(const float* __restrict__ K, const float* __restrict__ W1,
                         const float* __restrict__ W2, const float* __restrict__ W3,
                         const float* __restrict__ W4,
                         float* __restrict__ S, unsigned short* __restrict__ Kt,
                         unsigned short* __restrict__ W1t, unsigned short* __restrict__ W2t,
                         unsigned short* __restrict__ W3t, unsigned short* __restrict__ W4t)
{
  int idx = blockIdx.x * 256 + threadIdx.x;
  if (idx < 128) {
    float s = 0.f;
    for (int j = 0; j < 128; j++) { float v = K[idx * 128 + j]; s += v * v; }
    S[idx] = s;
  }
  int i = idx;
  if (i < 16384) {                       // Kt[n][k] = K[k][n]
    int n = i >> 7, k = i & 127;
    Kt[i] = f2bf(K[k * 128 + n]);
  } else if ((i -= 16384) < 224 * 128) { // W1t[n][k] = W1[k][n], n<200
    int n = i >> 7, k = i & 127;
    W1t[i] = f2bf(n < 200 ? W1[k * 200 + n] : 0.f);
  } else if ((i -= 28672) < 256 * 224) { // W2t[n][k] = W2[k][n], k<200
    int n = i / 224, k = i - n * 224;
    W2t[i] = f2bf(k < 200 ? W2[k * 256 + n] : 0.f);
  } else if ((i -= 57344) < 224 * 256) { // W3t[n][k] = W3[k][n], n<200
    int n = i >> 8, k = i & 255;
    W3t[i] = f2bf(n < 200 ? W3[k * 200 + n] : 0.f);
  } else if ((i -= 57344) < 128 * 224) { // W4t[n][k] = W4[k][n], k<200
    int n = i / 224, k = i - n * 224;
    W4t[i] = f2bf(k < 200 ? W4[k * 128 + n] : 0.f);
  }
}

// ---------------- generic MFMA layer: act(LDS) x Wt(global bf16) -> act(LDS) ----------------
template <int KP, int NT, int NREAL>
static __device__ __forceinline__ void gemm_layer(const unsigned short* __restrict__ wt,
                                                  const float* __restrict__ bias,
                                                  const unsigned short* actIn,
                                                  unsigned short* actOut,
                                                  int m, int qd, int wave)
{
  floatx4 acc[NT];
#pragma unroll
  for (int n = 0; n < NT; n++) acc[n] = {0.f, 0.f, 0.f, 0.f};
  for (int ks = 0; ks < KP / 32; ks++) {
    short8 a = *(const short8*)&actIn[(wave * 16 + m) * LSTR + ks * 32 + qd * 8];
#pragma unroll
    for (int n = 0; n < NT; n++) {
      short8 b = *(const short8*)&wt[(n * 16 + m) * KP + ks * 32 + qd * 8];
      acc[n] = __builtin_amdgcn_mfma_f32_16x16x32_bf16(a, b, acc[n], 0, 0, 0);
    }
  }
#pragma unroll
  for (int n = 0; n < NT; n++) {
    int col = n * 16 + m;
    float bv = (col < NREAL) ? bias[col] : 0.f;
#pragma unroll
    for (int i = 0; i < 4; i++) {
      float v = fmaxf(acc[n][i] + bv, 0.f);  // padded cols: 0+0 -> 0
      actOut[(wave * 16 + qd * 4 + i) * LSTR + col] = f2bf(v);
    }
  }
}

// ---------------- fused main kernel ----------------
__global__ __launch_bounds__(256, 2)
void dfm_main(const int* __restrict__ uidx, const int* __restrict__ iidx,
              const float* __restrict__ uemb, const float* __restrict__ iemb,
              const float* __restrict__ linw, const float* __restrict__ linb,
              const float* __restrict__ b1, const float* __restrict__ b2,
              const float* __restrict__ b3, const float* __restrict__ b4,
              const float* __restrict__ W5, const float* __restrict__ b5,
              const float* __restrict__ S, const unsigned short* __restrict__ Wc,
              const unsigned short* __restrict__ W2t, const unsigned short* __restrict__ W3t,
              const unsigned short* __restrict__ W4t,
              float* __restrict__ out)
{
  __shared__ unsigned short actA[BM * LSTR];
  __shared__ unsigned short actB[BM * LSTR];
  __shared__ float qrow[BM], linrow[BM], crossrow[BM], part[BM][4];

  const int t = threadIdx.x;
  const int lane = t & 63, wave = t >> 6;
  const int m = lane & 15, qd = lane >> 4;

  // ---- gather + linear + q = sum(x^2 * rowsum(K^2)) ----
  {
    int r = t >> 2, c = t & 3;
    int g = blockIdx.x * BM + r;
    int u = uidx[g], it = iidx[g];
    const float* up = uemb + (long)u * EMBD + c * 16;
    const float* ip = iemb + (long)it * EMBD + c * 16;
    float qp = 0.f;
#pragma unroll
    for (int j = 0; j < 16; j += 4) {
      float4 f = *(const float4*)(up + j);
      int col = c * 16 + j;
      float4 sv = *(const float4*)(S + col);
      ushortx4 h = {f2bf(f.x), f2bf(f.y), f2bf(f.z), f2bf(f.w)};
      *(ushortx4*)&actA[r * LSTR + col] = h;
      qp += f.x * f.x * sv.x + f.y * f.y * sv.y + f.z * f.z * sv.z + f.w * f.w * sv.w;
    }
#pragma unroll
    for (int j = 0; j < 16; j += 4) {
      float4 f = *(const float4*)(ip + j);
      int col = 64 + c * 16 + j;
      float4 sv = *(const float4*)(S + col);
      ushortx4 h = {f2bf(f.x), f2bf(f.y), f2bf(f.z), f2bf(f.w)};
      *(ushortx4*)&actA[r * LSTR + col] = h;
      qp += f.x * f.x * sv.x + f.y * f.y * sv.y + f.z * f.z * sv.z + f.w * f.w * sv.w;
    }
    part[r][c] = qp;
    if (c == 0) linrow[r] = linw[u] + linw[HASH_BINS + it] + linb[0];
  }
  __syncthreads();
  {
    int r = t >> 2, c = t & 3;
    if (c == 0) qrow[r] = part[r][0] + part[r][1] + part[r][2] + part[r][3];
  }
  __syncthreads();

  // ---- fused cross (NT 0..7) + layer1 (NT 8..21), K=128 ----
  {
    floatx4 acc[22];
#pragma unroll
    for (int n = 0; n < 22; n++) acc[n] = {0.f, 0.f, 0.f, 0.f};
    for (int ks = 0; ks < 4; ks++) {
      short8 a = *(const short8*)&actA[(wave * 16 + m) * LSTR + ks * 32 + qd * 8];
#pragma unroll
      for (int n = 0; n < 22; n++) {
        short8 b = *(const short8*)&Wc[(n * 16 + m) * 128 + ks * 32 + qd * 8];
        acc[n] = __builtin_amdgcn_mfma_f32_16x16x32_bf16(a, b, acc[n], 0, 0, 0);
      }
    }
    // cross: sum_j xk^2 per row, straight from accumulators
    float s0 = 0, s1 = 0, s2 = 0, s3 = 0;
#pragma unroll
    for (int n = 0; n < 8; n++) {
      s0 += acc[n][0] * acc[n][0];
      s1 += acc[n][1] * acc[n][1];
      s2 += acc[n][2] * acc[n][2];
      s3 += acc[n][3] * acc[n][3];
    }
#pragma unroll
    for (int mask = 1; mask < 16; mask <<= 1) {
      s0 += __shfl_xor(s0, mask, 64);
      s1 += __shfl_xor(s1, mask, 64);
      s2 += __shfl_xor(s2, mask, 64);
      s3 += __shfl_xor(s3, mask, 64);
    }
    if (m == 0) {
      int row = wave * 16 + qd * 4;
      const float inv = 0.5f / 128.f;
      crossrow[row + 0] = inv * (s0 - qrow[row + 0]);
      crossrow[row + 1] = inv * (s1 - qrow[row + 1]);
      crossrow[row + 2] = inv * (s2 - qrow[row + 2]);
      crossrow[row + 3] = inv * (s3 - qrow[row + 3]);
    }
    // layer1 epilogue: bias + relu -> actB (cols 200..223 become 0)
#pragma unroll
    for (int n = 8; n < 22; n++) {
      int col = (n - 8) * 16 + m;
      float bv = (col < 200) ? b1[col] : 0.f;
#pragma unroll
      for (int i = 0; i < 4; i++) {
        float v = fmaxf(acc[n][i] + bv, 0.f);
        actB[(wave * 16 + qd * 4 + i) * LSTR + col] = f2bf(v);
      }
    }
  }
  __syncthreads();

  gemm_layer<224, 16, 256>(W2t, b2, actB, actA, m, qd, wave);  // 224 -> 256
  __syncthreads();
  gemm_layer<256, 14, 200>(W3t, b3, actA, actB, m, qd, wave);  // 256 -> 224(200)
  __syncthreads();
  gemm_layer<224, 8, 128>(W4t, b4, actB, actA, m, qd, wave);   // 224 -> 128
  __syncthreads();

  // ---- final dot with W5 (fp32) + sigmoid ----
  {
    int r = t >> 2, c = t & 3;
    float d = 0.f;
#pragma unroll
    for (int k = 0; k < 32; k++) {
      int kk = c * 32 + k;
      d += bf2f(actA[r * LSTR + kk]) * W5[kk];
    }
    part[r][c] = d;
    __syncthreads();
    if (c == 0) {
      float logit = linrow[r] + crossrow[r] + part[r][0] + part[r][1] + part[r][2] + part[r][3] + b5[0];
      out[blockIdx.x * BM + r] = 1.f / (1.f + expf(-logit));
    }
  }
}

extern "C" void kernel_launch(void* const* d_in, const int* in_sizes, int n_in,
                              void* d_out, int out_size, void* d_ws, size_t ws_size,
                              hipStream_t stream)
{
  const int*   uidx = (const int*)d_in[0];
  const int*   iidx = (const int*)d_in[1];
  const float* uemb = (const float*)d_in[2];
  const float* iemb = (const float*)d_in[3];
  const float* linw = (const float*)d_in[4];
  const float* linb = (const float*)d_in[5];
  const float* K    = (const float*)d_in[6];
  const float* W1   = (const float*)d_in[7];
  const float* b1   = (const float*)d_in[8];
  const float* W2   = (const float*)d_in[9];
  const float* b2   = (const float*)d_in[10];
  const float* W3   = (const float*)d_in[11];
  const float* b3   = (const float*)d_in[12];
  const float* W4   = (const float*)d_in[13];
  const float* b4   = (const float*)d_in[14];
  const float* W5   = (const float*)d_in[15];
  const float* b5   = (const float*)d_in[16];

  char* w = (char*)d_ws;
  float* S = (float*)w;
  unsigned short* Kt  = (unsigned short*)(w + 512);
  unsigned short* W1t = (unsigned short*)(w + 33280);
  unsigned short* W2t = (unsigned short*)(w + 90624);
  unsigned short* W3t = (unsigned short*)(w + 205312);
  unsigned short* W4t = (unsigned short*)(w + 320000);
  float* out = (float*)d_out;

  dfm_prep<<<736, 256, 0, stream>>>(K, W1, W2, W3, W4, S, Kt, W1t, W2t, W3t, W4t);
  dfm_main<<<BATCH / BM, 256, 0, stream>>>(uidx, iidx, uemb, iemb, linw, linb,
                                           b1, b2, b3, b4, W5, b5,
                                           S, Kt, W2t, W3t, W4t, out);
}